// Round 3
// baseline (634.405 us; speedup 1.0000x reference)
//
#include <hip/hip_runtime.h>
#include <stdint.h>

#define BATCH   512
#define NFEAT   128
#define ESIZE   2048   // encoded feature size (bits)
#define HSIZE   8192
#define NCLS    10
#define THRESH_I 4
#define CAP     128    // max sparse entries per row (mean ~32); > CAP => dense
#define ROWB    64     // bytes per bit-plane row (512 batches / 8)

typedef float vf4 __attribute__((ext_vector_type(4)));  // nt-load-compatible

// Bit-plane layout: actT[h] is 64 bytes; byte beta, bit i  <->  batch beta+64*i.
//
// Bit-sliced accumulation (R1): per entry the lane's byte b is spread into
// per-bit byte-lane counters via two 32-bit multiplies:
//   sl = ((b&0xF) * 0x08040201 >> 3) & 0x01010101   // byte k = bit (3-k)
//   sh = ((b>>4)  * 0x08040201 >> 3) & 0x01010101   // byte k = bit (7-k)
// All partial-product positions 9i+j (i,j<4) are distinct and < 32 -> no
// carries. Counts <= CAP=128 (sparse) / ~60 (W0) << 255 -> no byte overflow.
// Entry sign is wave-uniform -> pos/neg accumulator branch is scalar.

// ---------------------------------------------------------------------------
// Encode: one wave per feature f; lane beta handles batches beta+64i.
// Produces actT0 rows e = f*16 + j. Also zeroes outAcc, the pad row of each
// bit-plane buffer (sentinel target), and the counts array for convert.
// ---------------------------------------------------------------------------
__global__ __launch_bounds__(256) void encode_kernel(
    const float* __restrict__ x,
    uint8_t* __restrict__ aT0, uint8_t* __restrict__ aT1,
    uint8_t* __restrict__ aT2, uint8_t* __restrict__ aT3,
    int* __restrict__ counts,
    float* __restrict__ outAcc) {
  int t = blockIdx.x * 256 + threadIdx.x;        // 8192 threads
  if (t < BATCH * NCLS) outAcc[t] = 0.0f;
  else if (t < 5120 + 64)  aT0[(size_t)ESIZE * ROWB + (t - 5120)] = 0;
  else if (t < 5184 + 64)  aT1[(size_t)HSIZE * ROWB + (t - 5184)] = 0;
  else if (t < 5248 + 64)  aT2[(size_t)HSIZE * ROWB + (t - 5248)] = 0;
  else if (t < 5312 + 64)  aT3[(size_t)HSIZE * ROWB + (t - 5312)] = 0;
  counts[t] = 0;
  counts[t + 8192] = 0;
  counts[t + 16384] = 0;

  int wave = threadIdx.x >> 6;
  int lane = threadIdx.x & 63;
  int f = blockIdx.x * 4 + wave;
  if (f < NFEAT) {
    float u[8];
#pragma unroll
    for (int i = 0; i < 8; ++i)
      u[i] = x[(size_t)(lane + 64 * i) * NFEAT + f] * 16.0f;
#pragma unroll
    for (int j = 0; j < 16; ++j) {
      uint32_t byte = 0;
#pragma unroll
      for (int i = 0; i < 8; ++i)
        byte |= (u[i] > (float)j ? 1u : 0u) << i;
      aT0[(size_t)(f * 16 + j) * ROWB + lane] = (uint8_t)byte;
    }
  }
}

// Spread helpers: bit (3-k) of nibble -> byte k of a u32.
__device__ __forceinline__ uint32_t spread_lo(uint32_t b) {
  return (((b & 0xFu) * 0x08040201u) >> 3) & 0x01010101u;
}
__device__ __forceinline__ uint32_t spread_hi(uint32_t b) {
  return (((b >> 4) * 0x08040201u) >> 3) & 0x01010101u;
}

// Decode 4 bit-sliced accumulators into the output activation byte.
__device__ __forceinline__ uint32_t decode_ob(uint32_t pL, uint32_t pH,
                                              uint32_t nL, uint32_t nH) {
  uint32_t ob = 0;
#pragma unroll
  for (int k = 0; k < 4; ++k) {
    int zl = (int)((pL >> (8 * k)) & 0xFFu) - (int)((nL >> (8 * k)) & 0xFFu);
    int zh = (int)((pH >> (8 * k)) & 0xFFu) - (int)((nH >> (8 * k)) & 0xFFu);
    ob |= (zl >= THRESH_I ? 1u : 0u) << (3 - k);
    ob |= (zh >= THRESH_I ? 1u : 0u) << (7 - k);
  }
  return ob;
}

// ---------------------------------------------------------------------------
// Convert (unit-parallel, fused): one wave per 2048-element aligned unit
// (8 KB, always within ONE row). Eight NON-TEMPORAL dwordx4 loads in flight
// (L1 bypass — validated earlier), then two 1024-elem groups.
//
// W0 (units 0..8191, one unit == one full row): layer 0 FUSED — scan ballot
// masks, bit-slice-accumulate from aT0 planes, write the aT1 byte directly.
// Hidden under the W1/W2 waves' HBM streaming.
//
// W1/W2: 16 ballots (SGPR-resident masks), one atomicAdd slot reservation,
// sparse scatter. Entry = (row_elem << 1) | (w<0).
// ---------------------------------------------------------------------------
__device__ __forceinline__ void cvt_group(
    const vf4* c, int gbase, int ebase, int wid, int lane, uint64_t lmask,
    uint32_t* __restrict__ lists, int* __restrict__ counts) {
  float v[16] = {c[0].x, c[0].y, c[0].z, c[0].w, c[1].x, c[1].y, c[1].z,
                 c[1].w, c[2].x, c[2].y, c[2].z, c[2].w, c[3].x, c[3].y,
                 c[3].z, c[3].w};
  uint64_t m[16];
  int tt[16];
#pragma unroll
  for (int k = 0; k < 16; ++k) {
    m[k] = __ballot(v[k] != 0.0f);
    tt[k] = (int)__popcll(m[k]);
  }
  int total = 0;
#pragma unroll
  for (int k = 0; k < 16; ++k) total += tt[k];
  if (total == 0) return;                            // wave-uniform

  int base = 0;
  if (lane == 0) base = atomicAdd(&counts[wid], total);
  base = __shfl(base, 0);

  uint32_t* lp = lists + (size_t)wid * CAP;
  int off = base;
#pragma unroll
  for (int k = 0; k < 16; ++k) {
    if (v[k] != 0.0f) {
      int pos = off + (int)__popcll(m[k] & lmask);
      int e = ebase + gbase + (k >> 2) * 256 + (k & 3) + lane * 4;
      if (pos < CAP)
        lp[pos] = ((uint32_t)e << 1) | (v[k] < 0.0f ? 1u : 0u);
    }
    off += tt[k];
  }
}

// Fused W0+layer0 group: scan nonzero masks, bit-slice accumulate from aT0.
__device__ __forceinline__ void fused_group(
    const vf4* c, int gbase, const uint8_t* __restrict__ aT0, int lane,
    uint32_t* pL, uint32_t* pH, uint32_t* nL, uint32_t* nH) {
  float v[16] = {c[0].x, c[0].y, c[0].z, c[0].w, c[1].x, c[1].y, c[1].z,
                 c[1].w, c[2].x, c[2].y, c[2].z, c[2].w, c[3].x, c[3].y,
                 c[3].z, c[3].w};
#pragma unroll
  for (int k = 0; k < 16; ++k) {
    uint64_t m = __ballot(v[k] != 0.0f);
    if (m == 0ull) continue;                         // wave-uniform
    uint64_t pm = __ballot(v[k] > 0.0f);
    int ebase = gbase + (k >> 2) * 256 + (k & 3);
    do {
      uint32_t src = (uint32_t)__builtin_ctzll(m);
      m &= m - 1;
      int e = ebase + 4 * (int)src;
      uint32_t b = (uint32_t)aT0[(size_t)e * ROWB + lane];
      uint32_t sl = spread_lo(b), sh = spread_hi(b);
      if ((pm >> src) & 1ull) { *pL += sl; *pH += sh; }   // wave-uniform
      else                    { *nL += sl; *nH += sh; }
    } while (m);
  }
}

__global__ __launch_bounds__(256, 8) void convert_kernel(
    const float* __restrict__ W0, const float* __restrict__ W1,
    const float* __restrict__ W2,
    const uint8_t* __restrict__ aT0, uint8_t* __restrict__ aT1,
    uint32_t* __restrict__ lists, int* __restrict__ counts) {
  int unit = (blockIdx.x * 256 + threadIdx.x) >> 6;  // 73728 units
  int lane = threadIdx.x & 63;

  if (unit < 8192) {
    // ---- W0 path: conversion + layer 0 fused (blocks 0..2047 exactly) ----
    int row = unit;
    const vf4* w4 = (const vf4*)(W0 + (size_t)row * (size_t)ESIZE);
    vf4 c[8];
#pragma unroll
    for (int j = 0; j < 8; ++j)
      c[j] = __builtin_nontemporal_load(w4 + j * 64 + lane);
    uint32_t pL = 0, pH = 0, nL = 0, nH = 0;
    fused_group(c,     0,    aT0, lane, &pL, &pH, &nL, &nH);
    fused_group(c + 4, 1024, aT0, lane, &pL, &pH, &nL, &nH);
    aT1[(size_t)row * ROWB + lane] = (uint8_t)decode_ob(pL, pH, nL, nH);
    return;
  }

  // ---- W1/W2 path: sparse-list conversion (unchanged) ----
  const float* W;
  int row, ebase, wid;
  if (unit < 8192 + 32768) {
    W = W1;
    int q = unit - 8192;
    row = q >> 2; ebase = (q & 3) * 2048; wid = HSIZE + row;
  } else {
    W = W2;
    int q = unit - 8192 - 32768;
    row = q >> 2; ebase = (q & 3) * 2048; wid = 2 * HSIZE + row;
  }

  const vf4* w4 = (const vf4*)(W + (size_t)row * HSIZE + (size_t)ebase);
  vf4 c[8];
#pragma unroll
  for (int j = 0; j < 8; ++j)
    c[j] = __builtin_nontemporal_load(w4 + j * 64 + lane);

  uint64_t lmask = (lane == 0) ? 0ull : (~0ull >> (64 - lane));
  cvt_group(c,     0,    ebase, wid, lane, lmask, lists, counts);
  cvt_group(c + 4, 1024, ebase, wid, lane, lmask, lists, counts);
}

// ---------------------------------------------------------------------------
// Sparse layer on bit-plane layout: per entry, lane loads ONE byte (the 8
// batches it owns) -> 64 B per wave per entry; bit-sliced accumulate.
// Tail group masked with sentinel e=P (zeroed pad row -> spread of 0).
// ---------------------------------------------------------------------------
__device__ __forceinline__ void proc_ent(uint32_t ent,
                                         const uint8_t* __restrict__ aIn,
                                         int lane,
                                         uint32_t* pL, uint32_t* pH,
                                         uint32_t* nL, uint32_t* nH) {
  uint32_t ee = ent >> 1;
  uint32_t b = (uint32_t)aIn[(size_t)ee * ROWB + lane];
  uint32_t sl = spread_lo(b), sh = spread_hi(b);
  if (ent & 1u) { *nL += sl; *nH += sh; }            // wave-uniform sign
  else          { *pL += sl; *pH += sh; }
}

__device__ __forceinline__ void proc_comp_dense(float v, int ebase,
                                                const uint8_t* __restrict__ aIn,
                                                int lane, int* z) {
  uint64_t m = __ballot(v != 0.0f);
  if (m == 0ull) return;
  uint64_t pm = __ballot(v > 0.0f);
  do {
    uint32_t src = (uint32_t)__builtin_ctzll(m);
    m &= m - 1;
    int e = ebase + 4 * (int)src;
    uint32_t negm = ((pm >> src) & 1ull) ? 0u : 0xFFFFFFFFu;
    uint32_t byte = (uint32_t)aIn[(size_t)e * ROWB + lane];
#pragma unroll
    for (int i = 0; i < 8; ++i) {
      uint32_t t = (byte >> i) & 1u;
      z[i] += (int)((t ^ negm) - negm);
    }
  } while (m);
}

template <int P>
__global__ __launch_bounds__(512, 4) void layer_kernel(
    const uint32_t* __restrict__ lists, const int* __restrict__ counts,
    const float* __restrict__ W,
    const uint8_t* __restrict__ aIn, uint8_t* __restrict__ aOut) {
  int wave = threadIdx.x >> 6;
  int lane = threadIdx.x & 63;
  int hbase = blockIdx.x * 16 + wave * 2;
  const uint32_t SENT = (uint32_t)(P << 1);

  for (int r = 0; r < 2; ++r) {
    int h = hbase + r;
    uint32_t ob;
    int cnt = counts[h];
    if (cnt <= CAP) {
      uint32_t pL = 0, pH = 0, nL = 0, nH = 0;
      const uint32_t* lp = lists + (size_t)h * CAP;
      int full = cnt & ~7;
      for (int i = 0; i < full; i += 8) {
        uint4 eA = *(const uint4*)(lp + i);
        uint4 eB = *(const uint4*)(lp + i + 4);
        proc_ent(eA.x, aIn, lane, &pL, &pH, &nL, &nH);
        proc_ent(eA.y, aIn, lane, &pL, &pH, &nL, &nH);
        proc_ent(eA.z, aIn, lane, &pL, &pH, &nL, &nH);
        proc_ent(eA.w, aIn, lane, &pL, &pH, &nL, &nH);
        proc_ent(eB.x, aIn, lane, &pL, &pH, &nL, &nH);
        proc_ent(eB.y, aIn, lane, &pL, &pH, &nL, &nH);
        proc_ent(eB.z, aIn, lane, &pL, &pH, &nL, &nH);
        proc_ent(eB.w, aIn, lane, &pL, &pH, &nL, &nH);
      }
      if (cnt & 7) {
        // tail: load the 8-group (within CAP slack), mask beyond cnt
        uint4 eA = *(const uint4*)(lp + full);
        uint4 eB = *(const uint4*)(lp + full + 4);
        uint32_t ee[8] = {eA.x, eA.y, eA.z, eA.w, eB.x, eB.y, eB.z, eB.w};
#pragma unroll
        for (int j = 0; j < 8; ++j)
          ee[j] = (full + j < cnt) ? ee[j] : SENT;
#pragma unroll
        for (int j = 0; j < 8; ++j)
          proc_ent(ee[j], aIn, lane, &pL, &pH, &nL, &nH);
      }
      ob = decode_ob(pL, pH, nL, nH);
    } else {
      // dense fallback (CAP overflow; effectively never taken)
      int z[8];
#pragma unroll
      for (int i = 0; i < 8; ++i) z[i] = 0;
      const float4* wrow = (const float4*)(W + (size_t)h * P) + lane;
      for (int it = 0; it < P / 256; ++it) {
        float4 wv = wrow[it * 64];
        int eb = it * 256;
        proc_comp_dense(wv.x, eb + 0, aIn, lane, z);
        proc_comp_dense(wv.y, eb + 1, aIn, lane, z);
        proc_comp_dense(wv.z, eb + 2, aIn, lane, z);
        proc_comp_dense(wv.w, eb + 3, aIn, lane, z);
      }
      ob = 0;
#pragma unroll
      for (int i = 0; i < 8; ++i)
        ob |= (z[i] >= THRESH_I ? 1u : 0u) << i;
    }

    aOut[(size_t)h * ROWB + lane] = (uint8_t)ob;
  }
}

// ---------------------------------------------------------------------------
// Output accumulation on bit planes. Chunk of 64 rows per block (384 blocks
// -> better CU coverage than 192); outConn chunk staged in LDS; per-thread
// acc[8][10]; LDS reduce then global atomics.
// ---------------------------------------------------------------------------
#define OCHUNK 64
__global__ __launch_bounds__(256, 4) void outacc_kernel(
    const float* __restrict__ outConn,
    const uint8_t* __restrict__ a1, const uint8_t* __restrict__ a2,
    const uint8_t* __restrict__ a3,
    float* __restrict__ outAcc) {
  __shared__ float shOC[OCHUNK][NCLS];
  __shared__ float shAcc[BATCH * NCLS];
  int tid = threadIdx.x;
  int gbase = blockIdx.x * OCHUNK;                 // 0..24512
  for (int idx = tid; idx < OCHUNK * NCLS; idx += 256)
    ((float*)shOC)[idx] = outConn[(size_t)gbase * NCLS + idx];
  for (int idx = tid; idx < BATCH * NCLS; idx += 256) shAcc[idx] = 0.0f;
  __syncthreads();

  int wave = tid >> 6;
  int lane = tid & 63;
  int layer = gbase >> 13;
  const uint8_t* aT = (layer == 0) ? a1 : (layer == 1) ? a2 : a3;
  int h0 = (gbase & (HSIZE - 1)) + wave * (OCHUNK / 4);

  float acc[8][NCLS];
#pragma unroll
  for (int i = 0; i < 8; ++i)
#pragma unroll
    for (int c = 0; c < NCLS; ++c) acc[i][c] = 0.0f;

  for (int r = 0; r < OCHUNK / 4; ++r) {
    int row = h0 + r;
    uint32_t byte = (uint32_t)aT[(size_t)row * ROWB + lane];
    float bf[8];
#pragma unroll
    for (int i = 0; i < 8; ++i) bf[i] = (float)((byte >> i) & 1u);
    const float* oc = shOC[wave * (OCHUNK / 4) + r];
#pragma unroll
    for (int c = 0; c < NCLS; ++c) {
      float o = oc[c];
#pragma unroll
      for (int i = 0; i < 8; ++i) acc[i][c] += bf[i] * o;
    }
  }
#pragma unroll
  for (int i = 0; i < 8; ++i)
#pragma unroll
    for (int c = 0; c < NCLS; ++c)
      atomicAdd(&shAcc[(size_t)(lane + 64 * i) * NCLS + c], acc[i][c]);
  __syncthreads();
  for (int idx = tid; idx < BATCH * NCLS; idx += 256)
    atomicAdd(&outAcc[idx], shAcc[idx]);
}

// ---------------------------------------------------------------------------
// Final: argmax per batch; write preds (int32) then outAct (f32) into d_out.
// ---------------------------------------------------------------------------
__global__ __launch_bounds__(256) void final_kernel(
    const float* __restrict__ outAcc,
    int* __restrict__ preds,
    float* __restrict__ outF) {
  int b = blockIdx.x * 256 + threadIdx.x;
  if (b < BATCH) {
    float vals[NCLS];
#pragma unroll
    for (int c = 0; c < NCLS; ++c) vals[c] = outAcc[b * NCLS + c];
    float best = vals[0];
    int bi = 0;
#pragma unroll
    for (int c = 1; c < NCLS; ++c) {
      if (vals[c] > best) { best = vals[c]; bi = c; }
    }
    preds[b] = bi;
#pragma unroll
    for (int c = 0; c < NCLS; ++c) outF[b * NCLS + c] = vals[c];
  }
}

extern "C" void kernel_launch(void* const* d_in, const int* in_sizes, int n_in,
                              void* d_out, int out_size, void* d_ws, size_t ws_size,
                              hipStream_t stream) {
  const float* x       = (const float*)d_in[1];
  const float* W0      = (const float*)d_in[2];
  const float* W1      = (const float*)d_in[3];
  const float* W2      = (const float*)d_in[4];
  const float* outConn = (const float*)d_in[5];

  uint8_t* base = (uint8_t*)d_ws;
  uint8_t* aT0 = base;                               // (2048+1)*64 B
  uint8_t* aT1 = base + 0x40000;                     // (8192+1)*64 B each
  uint8_t* aT2 = aT1 + 0x90000;
  uint8_t* aT3 = aT2 + 0x90000;
  uint32_t* lists = (uint32_t*)(aT3 + 0x90000);      // 24576*CAP words (+slack)
  int* counts = (int*)((uint8_t*)lists +
                       ((size_t)3 * HSIZE * CAP + 64) * 4);
  float* outAcc = (float*)(counts + 3 * HSIZE);

  encode_kernel<<<32, 256, 0, stream>>>(x, aT0, aT1, aT2, aT3, counts, outAcc);
  // 73728 units (2048 elems each) -> 18432 blocks of 256 (4 waves/block).
  // W0 units (first 2048 blocks) fuse layer 0 and write aT1 directly.
  convert_kernel<<<18432, 256, 0, stream>>>(W0, W1, W2, aT0, aT1, lists, counts);
  layer_kernel<HSIZE><<<512, 512, 0, stream>>>(
      lists + (size_t)HSIZE * CAP, counts + HSIZE, W1, aT1, aT2);
  layer_kernel<HSIZE><<<512, 512, 0, stream>>>(
      lists + (size_t)2 * HSIZE * CAP, counts + 2 * HSIZE, W2, aT2, aT3);
  outacc_kernel<<<384, 256, 0, stream>>>(outConn, aT1, aT2, aT3, outAcc);
  final_kernel<<<2, 256, 0, stream>>>(outAcc, (int*)d_out,
                                      (float*)d_out + BATCH);
}

// Round 4
// 600.162 us; speedup vs baseline: 1.0571x; 1.0571x over previous
//
#include <hip/hip_runtime.h>
#include <stdint.h>

#define BATCH   512
#define NFEAT   128
#define ESIZE   2048   // encoded feature size (bits)
#define HSIZE   8192
#define NCLS    10
#define THRESH_I 4
#define CAP     128    // max sparse entries per row (mean ~32); > CAP => dense
#define ROWB    64     // bytes per bit-plane row (512 batches / 8)

typedef float vf4 __attribute__((ext_vector_type(4)));  // nt-load-compatible

// Bit-plane layout: actT[h] is 64 bytes; byte beta, bit i  <->  batch beta+64*i.
//
// Branchless bit-sliced accumulation (R4): per entry the lane's byte b is
// complemented when the synapse is negative (b ^= 0xFF), then spread into
// per-bit byte-lane counters via two carry-free 32-bit multiplies:
//   sl = ((b&0xF) * 0x08040201 >> 3) & 0x01010101   // byte k = bit (3-k)
//   sh = ((b>>4)  * 0x08040201 >> 3) & 0x01010101   // byte k = bit (7-k)
// With nn = #negative entries:  acc = pos + (nn - neg)  =>  z = acc - nn.
// Counts <= CAP=128 << 255 -> no byte-lane overflow. No branches -> the
// compiler batches the unrolled byte loads (latency hiding preserved).

// ---------------------------------------------------------------------------
// Encode: one wave per feature f; lane beta handles batches beta+64i.
// Produces actT0 rows e = f*16 + j. Also zeroes outAcc, the pad row of each
// bit-plane buffer (sentinel target), and the counts array for convert.
// ---------------------------------------------------------------------------
__global__ __launch_bounds__(256) void encode_kernel(
    const float* __restrict__ x,
    uint8_t* __restrict__ aT0, uint8_t* __restrict__ aT1,
    uint8_t* __restrict__ aT2, uint8_t* __restrict__ aT3,
    int* __restrict__ counts,
    float* __restrict__ outAcc) {
  int t = blockIdx.x * 256 + threadIdx.x;        // 8192 threads
  if (t < BATCH * NCLS) outAcc[t] = 0.0f;
  else if (t < 5120 + 64)  aT0[(size_t)ESIZE * ROWB + (t - 5120)] = 0;
  else if (t < 5184 + 64)  aT1[(size_t)HSIZE * ROWB + (t - 5184)] = 0;
  else if (t < 5248 + 64)  aT2[(size_t)HSIZE * ROWB + (t - 5248)] = 0;
  else if (t < 5312 + 64)  aT3[(size_t)HSIZE * ROWB + (t - 5312)] = 0;
  counts[t] = 0;
  counts[t + 8192] = 0;
  counts[t + 16384] = 0;

  int wave = threadIdx.x >> 6;
  int lane = threadIdx.x & 63;
  int f = blockIdx.x * 4 + wave;
  if (f < NFEAT) {
    float u[8];
#pragma unroll
    for (int i = 0; i < 8; ++i)
      u[i] = x[(size_t)(lane + 64 * i) * NFEAT + f] * 16.0f;
#pragma unroll
    for (int j = 0; j < 16; ++j) {
      uint32_t byte = 0;
#pragma unroll
      for (int i = 0; i < 8; ++i)
        byte |= (u[i] > (float)j ? 1u : 0u) << i;
      aT0[(size_t)(f * 16 + j) * ROWB + lane] = (uint8_t)byte;
    }
  }
}

// Spread helpers: bit (3-k) of nibble -> byte k of a u32.
__device__ __forceinline__ uint32_t spread_lo(uint32_t b) {
  return (((b & 0xFu) * 0x08040201u) >> 3) & 0x01010101u;
}
__device__ __forceinline__ uint32_t spread_hi(uint32_t b) {
  return (((b >> 4) * 0x08040201u) >> 3) & 0x01010101u;
}

// Decode bit-sliced accumulators (+negative count) into the activation byte.
__device__ __forceinline__ uint32_t decode_nn(uint32_t aL, uint32_t aH,
                                              int nn) {
  uint32_t ob = 0;
#pragma unroll
  for (int k = 0; k < 4; ++k) {
    int zl = (int)((aL >> (8 * k)) & 0xFFu) - nn;
    int zh = (int)((aH >> (8 * k)) & 0xFFu) - nn;
    ob |= (zl >= THRESH_I ? 1u : 0u) << (3 - k);
    ob |= (zh >= THRESH_I ? 1u : 0u) << (7 - k);
  }
  return ob;
}

// ---------------------------------------------------------------------------
// Convert (unit-parallel, fused): one wave per 2048-element aligned unit
// (8 KB, always within ONE row). Eight NON-TEMPORAL dwordx4 loads in flight
// (L1 bypass — validated earlier), then two 1024-elem groups.
//
// W0 (units 0..8191, one unit == one full row): layer 0 FUSED — scan ballot
// masks, branchless bit-slice accumulate from aT0, write the aT1 byte.
// Hidden under the W1/W2 waves' HBM streaming.
//
// W1/W2: 16 ballots (SGPR-resident masks), one atomicAdd slot reservation,
// sparse scatter. Entry = (row_elem << 1) | (w<0).
// ---------------------------------------------------------------------------
__device__ __forceinline__ void cvt_group(
    const vf4* c, int gbase, int ebase, int wid, int lane, uint64_t lmask,
    uint32_t* __restrict__ lists, int* __restrict__ counts) {
  float v[16] = {c[0].x, c[0].y, c[0].z, c[0].w, c[1].x, c[1].y, c[1].z,
                 c[1].w, c[2].x, c[2].y, c[2].z, c[2].w, c[3].x, c[3].y,
                 c[3].z, c[3].w};
  uint64_t m[16];
  int tt[16];
#pragma unroll
  for (int k = 0; k < 16; ++k) {
    m[k] = __ballot(v[k] != 0.0f);
    tt[k] = (int)__popcll(m[k]);
  }
  int total = 0;
#pragma unroll
  for (int k = 0; k < 16; ++k) total += tt[k];
  if (total == 0) return;                            // wave-uniform

  int base = 0;
  if (lane == 0) base = atomicAdd(&counts[wid], total);
  base = __shfl(base, 0);

  uint32_t* lp = lists + (size_t)wid * CAP;
  int off = base;
#pragma unroll
  for (int k = 0; k < 16; ++k) {
    if (v[k] != 0.0f) {
      int pos = off + (int)__popcll(m[k] & lmask);
      int e = ebase + gbase + (k >> 2) * 256 + (k & 3) + lane * 4;
      if (pos < CAP)
        lp[pos] = ((uint32_t)e << 1) | (v[k] < 0.0f ? 1u : 0u);
    }
    off += tt[k];
  }
}

// Fused W0+layer0 group: branchless bit-slice accumulate from aT0.
__device__ __forceinline__ void fused_group(
    const vf4* c, int gbase, const uint8_t* __restrict__ aT0, int lane,
    uint32_t* aL, uint32_t* aH, int* nn) {
  float v[16] = {c[0].x, c[0].y, c[0].z, c[0].w, c[1].x, c[1].y, c[1].z,
                 c[1].w, c[2].x, c[2].y, c[2].z, c[2].w, c[3].x, c[3].y,
                 c[3].z, c[3].w};
#pragma unroll
  for (int k = 0; k < 16; ++k) {
    uint64_t m = __ballot(v[k] != 0.0f);
    if (m == 0ull) continue;                         // wave-uniform
    uint64_t pm = __ballot(v[k] > 0.0f);
    *nn += (int)__popcll(m & ~pm);                   // negatives this subgroup
    int ebase = gbase + (k >> 2) * 256 + (k & 3);
    do {
      uint32_t src = (uint32_t)__builtin_ctzll(m);
      m &= m - 1;
      int e = ebase + 4 * (int)src;
      uint32_t b = (uint32_t)aT0[(size_t)e * ROWB + lane];
      uint32_t s = (uint32_t)((pm >> src) & 1ull);   // 1 if positive
      b ^= (s - 1u) & 0xFFu;                         // complement if negative
      *aL += spread_lo(b);
      *aH += spread_hi(b);
    } while (m);
  }
}

__global__ __launch_bounds__(256, 8) void convert_kernel(
    const float* __restrict__ W0, const float* __restrict__ W1,
    const float* __restrict__ W2,
    const uint8_t* __restrict__ aT0, uint8_t* __restrict__ aT1,
    uint32_t* __restrict__ lists, int* __restrict__ counts) {
  int unit = (blockIdx.x * 256 + threadIdx.x) >> 6;  // 73728 units
  int lane = threadIdx.x & 63;

  if (unit < 8192) {
    // ---- W0 path: conversion + layer 0 fused (blocks 0..2047 exactly) ----
    int row = unit;
    const vf4* w4 = (const vf4*)(W0 + (size_t)row * (size_t)ESIZE);
    vf4 c[8];
#pragma unroll
    for (int j = 0; j < 8; ++j)
      c[j] = __builtin_nontemporal_load(w4 + j * 64 + lane);
    uint32_t aL = 0, aH = 0;
    int nn = 0;
    fused_group(c,     0,    aT0, lane, &aL, &aH, &nn);
    fused_group(c + 4, 1024, aT0, lane, &aL, &aH, &nn);
    aT1[(size_t)row * ROWB + lane] = (uint8_t)decode_nn(aL, aH, nn);
    return;
  }

  // ---- W1/W2 path: sparse-list conversion (unchanged) ----
  const float* W;
  int row, ebase, wid;
  if (unit < 8192 + 32768) {
    W = W1;
    int q = unit - 8192;
    row = q >> 2; ebase = (q & 3) * 2048; wid = HSIZE + row;
  } else {
    W = W2;
    int q = unit - 8192 - 32768;
    row = q >> 2; ebase = (q & 3) * 2048; wid = 2 * HSIZE + row;
  }

  const vf4* w4 = (const vf4*)(W + (size_t)row * HSIZE + (size_t)ebase);
  vf4 c[8];
#pragma unroll
  for (int j = 0; j < 8; ++j)
    c[j] = __builtin_nontemporal_load(w4 + j * 64 + lane);

  uint64_t lmask = (lane == 0) ? 0ull : (~0ull >> (64 - lane));
  cvt_group(c,     0,    ebase, wid, lane, lmask, lists, counts);
  cvt_group(c + 4, 1024, ebase, wid, lane, lmask, lists, counts);
}

// ---------------------------------------------------------------------------
// Sparse layer on bit-plane layout: per entry, lane loads ONE byte (the 8
// batches it owns) -> 64 B per wave per entry; branchless bit-sliced
// accumulate. Tail group masked with sentinel e=P (zeroed pad row, sign 0
// -> contributes 0 to acc and 0 to nn).
// ---------------------------------------------------------------------------
__device__ __forceinline__ void proc_ent(uint32_t ent,
                                         const uint8_t* __restrict__ aIn,
                                         int lane,
                                         uint32_t* aL, uint32_t* aH,
                                         int* nn) {
  uint32_t ee = ent >> 1;
  uint32_t s = ent & 1u;                             // 1 if negative
  uint32_t b = (uint32_t)aIn[(size_t)ee * ROWB + lane];
  b ^= (0u - s) & 0xFFu;                             // complement if negative
  *aL += spread_lo(b);
  *aH += spread_hi(b);
  *nn += (int)s;
}

__device__ __forceinline__ void proc_comp_dense(float v, int ebase,
                                                const uint8_t* __restrict__ aIn,
                                                int lane, int* z) {
  uint64_t m = __ballot(v != 0.0f);
  if (m == 0ull) return;
  uint64_t pm = __ballot(v > 0.0f);
  do {
    uint32_t src = (uint32_t)__builtin_ctzll(m);
    m &= m - 1;
    int e = ebase + 4 * (int)src;
    uint32_t negm = ((pm >> src) & 1ull) ? 0u : 0xFFFFFFFFu;
    uint32_t byte = (uint32_t)aIn[(size_t)e * ROWB + lane];
#pragma unroll
    for (int i = 0; i < 8; ++i) {
      uint32_t t = (byte >> i) & 1u;
      z[i] += (int)((t ^ negm) - negm);
    }
  } while (m);
}

template <int P>
__global__ __launch_bounds__(512, 4) void layer_kernel(
    const uint32_t* __restrict__ lists, const int* __restrict__ counts,
    const float* __restrict__ W,
    const uint8_t* __restrict__ aIn, uint8_t* __restrict__ aOut) {
  int wave = threadIdx.x >> 6;
  int lane = threadIdx.x & 63;
  int hbase = blockIdx.x * 16 + wave * 2;
  const uint32_t SENT = (uint32_t)(P << 1);

  for (int r = 0; r < 2; ++r) {
    int h = hbase + r;
    uint32_t ob;
    int cnt = counts[h];
    if (cnt <= CAP) {
      uint32_t aL = 0, aH = 0;
      int nn = 0;
      const uint32_t* lp = lists + (size_t)h * CAP;
      int full = cnt & ~7;
      for (int i = 0; i < full; i += 8) {
        uint4 eA = *(const uint4*)(lp + i);
        uint4 eB = *(const uint4*)(lp + i + 4);
        proc_ent(eA.x, aIn, lane, &aL, &aH, &nn);
        proc_ent(eA.y, aIn, lane, &aL, &aH, &nn);
        proc_ent(eA.z, aIn, lane, &aL, &aH, &nn);
        proc_ent(eA.w, aIn, lane, &aL, &aH, &nn);
        proc_ent(eB.x, aIn, lane, &aL, &aH, &nn);
        proc_ent(eB.y, aIn, lane, &aL, &aH, &nn);
        proc_ent(eB.z, aIn, lane, &aL, &aH, &nn);
        proc_ent(eB.w, aIn, lane, &aL, &aH, &nn);
      }
      if (cnt & 7) {
        // tail: load the 8-group (within CAP slack), mask beyond cnt
        uint4 eA = *(const uint4*)(lp + full);
        uint4 eB = *(const uint4*)(lp + full + 4);
        uint32_t ee[8] = {eA.x, eA.y, eA.z, eA.w, eB.x, eB.y, eB.z, eB.w};
#pragma unroll
        for (int j = 0; j < 8; ++j)
          ee[j] = (full + j < cnt) ? ee[j] : SENT;
#pragma unroll
        for (int j = 0; j < 8; ++j)
          proc_ent(ee[j], aIn, lane, &aL, &aH, &nn);
      }
      ob = decode_nn(aL, aH, nn);
    } else {
      // dense fallback (CAP overflow; effectively never taken)
      int z[8];
#pragma unroll
      for (int i = 0; i < 8; ++i) z[i] = 0;
      const float4* wrow = (const float4*)(W + (size_t)h * P) + lane;
      for (int it = 0; it < P / 256; ++it) {
        float4 wv = wrow[it * 64];
        int eb = it * 256;
        proc_comp_dense(wv.x, eb + 0, aIn, lane, z);
        proc_comp_dense(wv.y, eb + 1, aIn, lane, z);
        proc_comp_dense(wv.z, eb + 2, aIn, lane, z);
        proc_comp_dense(wv.w, eb + 3, aIn, lane, z);
      }
      ob = 0;
#pragma unroll
      for (int i = 0; i < 8; ++i)
        ob |= (z[i] >= THRESH_I ? 1u : 0u) << i;
    }

    aOut[(size_t)h * ROWB + lane] = (uint8_t)ob;
  }
}

// ---------------------------------------------------------------------------
// Output accumulation on bit planes. Chunk of 128 rows per block (192 blocks
// — the per-block 5120-word global-atomic flush dominates; fewer blocks =
// less contention, validated R3 vs R1); outConn chunk staged in LDS;
// per-thread acc[8][10]; LDS reduce then global atomics.
// ---------------------------------------------------------------------------
#define OCHUNK 128
__global__ __launch_bounds__(256, 4) void outacc_kernel(
    const float* __restrict__ outConn,
    const uint8_t* __restrict__ a1, const uint8_t* __restrict__ a2,
    const uint8_t* __restrict__ a3,
    float* __restrict__ outAcc) {
  __shared__ float shOC[OCHUNK][NCLS];
  __shared__ float shAcc[BATCH * NCLS];
  int tid = threadIdx.x;
  int gbase = blockIdx.x * OCHUNK;                 // 0..24448
  for (int idx = tid; idx < OCHUNK * NCLS; idx += 256)
    ((float*)shOC)[idx] = outConn[(size_t)gbase * NCLS + idx];
  for (int idx = tid; idx < BATCH * NCLS; idx += 256) shAcc[idx] = 0.0f;
  __syncthreads();

  int wave = tid >> 6;
  int lane = tid & 63;
  int layer = gbase >> 13;
  const uint8_t* aT = (layer == 0) ? a1 : (layer == 1) ? a2 : a3;
  int h0 = (gbase & (HSIZE - 1)) + wave * 32;

  float acc[8][NCLS];
#pragma unroll
  for (int i = 0; i < 8; ++i)
#pragma unroll
    for (int c = 0; c < NCLS; ++c) acc[i][c] = 0.0f;

  for (int r = 0; r < 32; ++r) {
    int row = h0 + r;
    uint32_t byte = (uint32_t)aT[(size_t)row * ROWB + lane];
    float bf[8];
#pragma unroll
    for (int i = 0; i < 8; ++i) bf[i] = (float)((byte >> i) & 1u);
    const float* oc = shOC[wave * 32 + r];
#pragma unroll
    for (int c = 0; c < NCLS; ++c) {
      float o = oc[c];
#pragma unroll
      for (int i = 0; i < 8; ++i) acc[i][c] += bf[i] * o;
    }
  }
#pragma unroll
  for (int i = 0; i < 8; ++i)
#pragma unroll
    for (int c = 0; c < NCLS; ++c)
      atomicAdd(&shAcc[(size_t)(lane + 64 * i) * NCLS + c], acc[i][c]);
  __syncthreads();
  for (int idx = tid; idx < BATCH * NCLS; idx += 256)
    atomicAdd(&outAcc[idx], shAcc[idx]);
}

// ---------------------------------------------------------------------------
// Final: argmax per batch; write preds (int32) then outAct (f32) into d_out.
// ---------------------------------------------------------------------------
__global__ __launch_bounds__(256) void final_kernel(
    const float* __restrict__ outAcc,
    int* __restrict__ preds,
    float* __restrict__ outF) {
  int b = blockIdx.x * 256 + threadIdx.x;
  if (b < BATCH) {
    float vals[NCLS];
#pragma unroll
    for (int c = 0; c < NCLS; ++c) vals[c] = outAcc[b * NCLS + c];
    float best = vals[0];
    int bi = 0;
#pragma unroll
    for (int c = 1; c < NCLS; ++c) {
      if (vals[c] > best) { best = vals[c]; bi = c; }
    }
    preds[b] = bi;
#pragma unroll
    for (int c = 0; c < NCLS; ++c) outF[b * NCLS + c] = vals[c];
  }
}

extern "C" void kernel_launch(void* const* d_in, const int* in_sizes, int n_in,
                              void* d_out, int out_size, void* d_ws, size_t ws_size,
                              hipStream_t stream) {
  const float* x       = (const float*)d_in[1];
  const float* W0      = (const float*)d_in[2];
  const float* W1      = (const float*)d_in[3];
  const float* W2      = (const float*)d_in[4];
  const float* outConn = (const float*)d_in[5];

  uint8_t* base = (uint8_t*)d_ws;
  uint8_t* aT0 = base;                               // (2048+1)*64 B
  uint8_t* aT1 = base + 0x40000;                     // (8192+1)*64 B each
  uint8_t* aT2 = aT1 + 0x90000;
  uint8_t* aT3 = aT2 + 0x90000;
  uint32_t* lists = (uint32_t*)(aT3 + 0x90000);      // 24576*CAP words (+slack)
  int* counts = (int*)((uint8_t*)lists +
                       ((size_t)3 * HSIZE * CAP + 64) * 4);
  float* outAcc = (float*)(counts + 3 * HSIZE);

  encode_kernel<<<32, 256, 0, stream>>>(x, aT0, aT1, aT2, aT3, counts, outAcc);
  // 73728 units (2048 elems each) -> 18432 blocks of 256 (4 waves/block).
  // W0 units (first 2048 blocks) fuse layer 0 and write aT1 directly.
  convert_kernel<<<18432, 256, 0, stream>>>(W0, W1, W2, aT0, aT1, lists, counts);
  layer_kernel<HSIZE><<<512, 512, 0, stream>>>(
      lists + (size_t)HSIZE * CAP, counts + HSIZE, W1, aT1, aT2);
  layer_kernel<HSIZE><<<512, 512, 0, stream>>>(
      lists + (size_t)2 * HSIZE * CAP, counts + 2 * HSIZE, W2, aT2, aT3);
  outacc_kernel<<<192, 256, 0, stream>>>(outConn, aT1, aT2, aT3, outAcc);
  final_kernel<<<2, 256, 0, stream>>>(outAcc, (int*)d_out,
                                      (float*)d_out + BATCH);
}